// Round 2
// baseline (835.494 us; speedup 1.0000x reference)
//
#include <hip/hip_runtime.h>

// MoE top-2 of 8 experts. B=4096 tokens, D=1024, H=4096.
// Round 2: pre-transpose weights to bf16 [n][k]; GEMMs use global_load_lds
// (m97 structure). H split into 2 passes of 2048 so ws fits 92.5 MB.

typedef __attribute__((ext_vector_type(8))) short short8;
typedef __attribute__((ext_vector_type(4))) float f32x4;

#define B_TOK 4096
#define D_DIM 1024
#define H_DIM 4096
#define N_EXP 8
#define H_HALF 2048

__device__ __forceinline__ unsigned short f2bf(float f) {
  unsigned int u = __float_as_uint(f);
  u += 0x7fffu + ((u >> 16) & 1u);  // RNE
  return (unsigned short)(u >> 16);
}
__device__ __forceinline__ float bf2f(unsigned short s) {
  return __uint_as_float(((unsigned int)s) << 16);
}

__device__ __forceinline__ void async_ld16(const void* g, void* l) {
  __builtin_amdgcn_global_load_lds(
      (const __attribute__((address_space(1))) void*)g,
      (__attribute__((address_space(3))) void*)l, 16, 0, 0);
}

// ---------------- x -> bf16 ----------------
__global__ __launch_bounds__(256) void convert_x_kernel(const float* __restrict__ x,
                                                        unsigned short* __restrict__ xb) {
  const size_t i = ((size_t)blockIdx.x * 256 + threadIdx.x) * 4;
  float4 v = *(const float4*)(x + i);
  ushort4 r;
  r.x = f2bf(v.x); r.y = f2bf(v.y); r.z = f2bf(v.z); r.w = f2bf(v.w);
  *(ushort4*)(xb + i) = r;
}

// ---------------- gating: fp64 logits, top-2, bucket ----------------
__global__ __launch_bounds__(256) void gating_kernel(
    const float* __restrict__ x, const float* __restrict__ wg,
    int* __restrict__ counts, float* __restrict__ importance,
    int* __restrict__ bucket, int* __restrict__ tok_e,
    int* __restrict__ tok_p, float* __restrict__ tok_g) {
  const int lane = threadIdx.x & 63;
  const int t = blockIdx.x * 4 + (threadIdx.x >> 6);
  const float* xr = x + (size_t)t * D_DIM;
  double acc[8] = {0, 0, 0, 0, 0, 0, 0, 0};
  for (int d = lane; d < D_DIM; d += 64) {
    double xv = (double)xr[d];
    const float4 w0 = *(const float4*)(wg + d * 8);
    const float4 w1 = *(const float4*)(wg + d * 8 + 4);
    acc[0] += xv * (double)w0.x; acc[1] += xv * (double)w0.y;
    acc[2] += xv * (double)w0.z; acc[3] += xv * (double)w0.w;
    acc[4] += xv * (double)w1.x; acc[5] += xv * (double)w1.y;
    acc[6] += xv * (double)w1.z; acc[7] += xv * (double)w1.w;
  }
#pragma unroll
  for (int e = 0; e < 8; ++e) {
    double v = acc[e];
#pragma unroll
    for (int m = 32; m > 0; m >>= 1) v += __shfl_xor(v, m, 64);
    acc[e] = v;
  }
  if (lane == 0) {
    double b1v = -1e300, b2v = -1e300;
    int i1 = 0, i2 = 0;
#pragma unroll
    for (int e = 0; e < 8; ++e) {
      double v = acc[e];
      if (v > b1v) { b2v = b1v; i2 = i1; b1v = v; i1 = e; }
      else if (v > b2v) { b2v = v; i2 = e; }
    }
    float ex = expf((float)b2v - (float)b1v);
    float den = 1.f + ex;
    float g1 = 1.f / den, g2 = ex / den;
    int p1 = atomicAdd(&counts[i1], 1);
    int p2 = atomicAdd(&counts[i2], 1);
    bucket[i1 * B_TOK + p1] = t;
    bucket[i2 * B_TOK + p2] = t;
    tok_e[2 * t] = i1; tok_e[2 * t + 1] = i2;
    tok_p[2 * t] = p1; tok_p[2 * t + 1] = p2;
    tok_g[2 * t] = g1; tok_g[2 * t + 1] = g2;
    atomicAdd(&importance[i1], g1);
    atomicAdd(&importance[i2], g2);
  }
}

// ---------------- prefix offsets + balancing loss ----------------
__global__ void finalize_kernel(const int* __restrict__ counts,
                                const float* __restrict__ importance,
                                const float* __restrict__ coef,
                                int* __restrict__ offs, float* __restrict__ loss_out) {
  if (threadIdx.x == 0 && blockIdx.x == 0) {
    int o = 0;
    for (int e = 0; e < 8; ++e) { offs[e] = o; o += counts[e]; }
    offs[8] = o;
    double mi = 0, ml = 0;
    for (int e = 0; e < 8; ++e) { mi += (double)importance[e]; ml += (double)counts[e]; }
    mi *= 0.125; ml *= 0.125;
    double vi = 0, vl = 0;
    for (int e = 0; e < 8; ++e) {
      double di = (double)importance[e] - mi; vi += di * di;
      double dl = (double)counts[e]    - ml; vl += dl * dl;
    }
    vi /= 7.0; vl /= 7.0;
    double loss = (vi / (mi * mi + 1e-10) + vl / (ml * ml + 1e-10)) * (double)coef[0];
    *loss_out = (float)loss;
  }
}

// ---------------- weight transpose: fp32 [k][n] tile -> bf16 [n][k] ----------------
__global__ __launch_bounds__(256) void transpose_w_kernel(
    const float* __restrict__ W, unsigned short* __restrict__ Wt,
    int ND_src, int k_base, int n_base, int KD_out,
    size_t w_stride_e, size_t wt_stride_e) {
  const int e = blockIdx.z;
  const int kt = blockIdx.x * 64;
  const int nt = blockIdx.y * 64;
  const float* We = W + (size_t)e * w_stride_e + (size_t)(k_base + kt) * ND_src + n_base + nt;
  unsigned short* Wte = Wt + (size_t)e * wt_stride_e + (size_t)nt * KD_out + kt;
  __shared__ unsigned short Tl[64][64];
  const int t = threadIdx.x;
  const int rk = (t & 15) * 4;   // k within tile (low bits -> good LDS banking)
  const int rn = (t >> 4) * 4;   // n within tile
  float4 r[4];
#pragma unroll
  for (int j = 0; j < 4; ++j)
    r[j] = *(const float4*)(We + (size_t)(rk + j) * ND_src + rn);
#pragma unroll
  for (int i = 0; i < 4; ++i) {
    ushort4 v;
    v.x = f2bf(((const float*)&r[0])[i]);
    v.y = f2bf(((const float*)&r[1])[i]);
    v.z = f2bf(((const float*)&r[2])[i]);
    v.w = f2bf(((const float*)&r[3])[i]);
    *(ushort4*)&Tl[rn + i][rk] = v;
  }
  __syncthreads();
  const int on = t >> 2, oc = (t & 3) * 16;
  uint4 o0 = *(const uint4*)&Tl[on][oc];
  uint4 o1 = *(const uint4*)&Tl[on][oc + 8];
  uint4* dst = (uint4*)(Wte + (size_t)on * KD_out + oc);
  dst[0] = o0;
  dst[1] = o1;
}

// ---------------- grouped GEMM: 128x128 tile, BK=32, global_load_lds both operands ----
// A: bf16 rows stride KDIM (gathered tokens or contiguous slots). Bt: bf16 [E][NDIM][KDIM].
template <int KDIM, int NDIM, bool GATHER, bool RELU, bool ACCUM>
__global__ __launch_bounds__(256) void grouped_gemm(
    const unsigned short* __restrict__ A, const unsigned short* __restrict__ Bt,
    const float* __restrict__ bias, int biasN,
    const int* __restrict__ counts, const int* __restrict__ offs,
    const int* __restrict__ bucket, unsigned short* __restrict__ Out, int outN) {
  const int e = blockIdx.z;
  const int n_e = counts[e];
  const int row0 = blockIdx.y * 128;
  if (row0 >= n_e) return;
  const int m_cnt = min(128, n_e - row0);
  const int n0 = blockIdx.x * 128;
  const int slot0 = offs[e] + row0;

  __shared__ unsigned short Alds[128][32];  // unpadded: global_load_lds layout
  __shared__ unsigned short Blds[128][32];
  __shared__ int toklds[128];

  const int tid = threadIdx.x;
  const int lane = tid & 63;
  const int wid = tid >> 6;
  const int q = lane >> 4, l15 = lane & 15;
  const int wm = (wid >> 1) * 64, wn = (wid & 1) * 64;

  if (GATHER) {
    if (tid < 128) toklds[tid] = bucket[e * B_TOK + row0 + min(tid, m_cnt - 1)];
    __syncthreads();
  }
  // chunk c = tid (and tid+256): row = c>>2, 16B k-chunk = c&3; LDS byte off = c*16
  const int r0 = tid >> 2;
  const int kc = (tid & 3) * 8;  // elements
  size_t ga0, ga1;
  if (GATHER) {
    ga0 = (size_t)toklds[r0] * KDIM + kc;
    ga1 = (size_t)toklds[r0 + 64] * KDIM + kc;
  } else {
    ga0 = (size_t)(slot0 + min(r0, m_cnt - 1)) * KDIM + kc;
    ga1 = (size_t)(slot0 + min(r0 + 64, m_cnt - 1)) * KDIM + kc;
  }
  const unsigned short* bbase =
      Bt + (size_t)e * NDIM * KDIM + (size_t)(n0 + r0) * KDIM + kc;
  char* aldsw = (char*)Alds + wid * 1024;  // wave-uniform LDS base (+ lane*16 by HW)
  char* bldsw = (char*)Blds + wid * 1024;

  f32x4 acc[4][4] = {};
  for (int k0 = 0; k0 < KDIM; k0 += 32) {
    async_ld16(A + ga0 + k0, aldsw);
    async_ld16(A + ga1 + k0, aldsw + 4096);
    async_ld16(bbase + k0, bldsw);
    async_ld16(bbase + (size_t)64 * KDIM + k0, bldsw + 4096);
    __syncthreads();  // drains vmcnt(0): staged data visible
    short8 af[4], bfr[4];
#pragma unroll
    for (int mi = 0; mi < 4; ++mi) af[mi] = *(const short8*)&Alds[wm + mi * 16 + l15][q * 8];
#pragma unroll
    for (int ni = 0; ni < 4; ++ni) bfr[ni] = *(const short8*)&Blds[wn + ni * 16 + l15][q * 8];
#pragma unroll
    for (int mi = 0; mi < 4; ++mi)
#pragma unroll
      for (int ni = 0; ni < 4; ++ni)
        acc[mi][ni] = __builtin_amdgcn_mfma_f32_16x16x32_bf16(af[mi], bfr[ni], acc[mi][ni], 0, 0, 0);
    __syncthreads();  // frag reads done before next overwrite
  }

  // epilogue: C/D layout col=lane&15, row=(lane>>4)*4+reg
  const float* be = bias + (size_t)e * biasN + n0;
#pragma unroll
  for (int ni = 0; ni < 4; ++ni) {
    const int c = wn + ni * 16 + l15;
    const float bv = ACCUM ? 0.f : be[c];
#pragma unroll
    for (int mi = 0; mi < 4; ++mi) {
      const int rb = wm + mi * 16 + q * 4;
#pragma unroll
      for (int rg = 0; rg < 4; ++rg) {
        const int r = rb + rg;
        if (r < m_cnt) {
          float v = acc[mi][ni][rg] + bv;
          if (RELU) v = fmaxf(v, 0.f);
          unsigned short* op = Out + (size_t)(slot0 + r) * outN + n0 + c;
          if (ACCUM) v += bf2f(*op);
          *op = f2bf(v);
        }
      }
    }
  }
}

// ---------------- combine ----------------
__device__ __forceinline__ float comb1(float a, float b, float g1, float g2) {
  float c = g1 * expf(a) + g2 * expf(b);
  if (c == 0.f) c = 2.220446049250313e-16f;
  return logf(c);
}

__global__ __launch_bounds__(256) void combine_kernel(
    const unsigned short* __restrict__ o_buf, const int* __restrict__ offs,
    const int* __restrict__ tok_e, const int* __restrict__ tok_p,
    const float* __restrict__ tok_g, float* __restrict__ y) {
  const int t = blockIdx.x;
  const int e1 = tok_e[2 * t], e2 = tok_e[2 * t + 1];
  const int s1 = offs[e1] + tok_p[2 * t];
  const int s2 = offs[e2] + tok_p[2 * t + 1];
  const float g1 = tok_g[2 * t], g2 = tok_g[2 * t + 1];
  const int i = threadIdx.x * 4;
  ushort4 a4 = *(const ushort4*)(o_buf + (size_t)s1 * D_DIM + i);
  ushort4 b4 = *(const ushort4*)(o_buf + (size_t)s2 * D_DIM + i);
  float4 r;
  r.x = comb1(bf2f(a4.x), bf2f(b4.x), g1, g2);
  r.y = comb1(bf2f(a4.y), bf2f(b4.y), g1, g2);
  r.z = comb1(bf2f(a4.z), bf2f(b4.z), g1, g2);
  r.w = comb1(bf2f(a4.w), bf2f(b4.w), g1, g2);
  *(float4*)(y + (size_t)t * D_DIM + i) = r;
}

// ---------------- launch ----------------
extern "C" void kernel_launch(void* const* d_in, const int* in_sizes, int n_in,
                              void* d_out, int out_size, void* d_ws, size_t ws_size,
                              hipStream_t stream) {
  const float* x  = (const float*)d_in[0];
  const float* wg = (const float*)d_in[1];
  const float* W1 = (const float*)d_in[2];
  const float* b1 = (const float*)d_in[3];
  const float* W2 = (const float*)d_in[4];
  const float* b2 = (const float*)d_in[5];
  const float* cf = (const float*)d_in[6];
  float* y = (float*)d_out;

  char* w = (char*)d_ws;
  unsigned short* x_bf = (unsigned short*)(w);              // 8,388,608 B
  int*   counts = (int*)(w + 8388608);
  float* imp    = (float*)(w + 8388640);
  int*   offs   = (int*)(w + 8388672);
  int*   tok_e  = (int*)(w + 8388736);
  int*   tok_p  = (int*)(w + 8421504);
  float* tok_g  = (float*)(w + 8454272);
  int*   bucket = (int*)(w + 8487040);                      // ends 8,618,112
  unsigned short* wt     = (unsigned short*)(w + 8618112);  // 33,554,432 B (W1t/W2t, serial)
  unsigned short* h_half = (unsigned short*)(w + 42172544); // 33,554,432 B
  unsigned short* o_buf  = (unsigned short*)(w + 75726976); // 16,777,216 B -> 92,504,192
  if (ws_size < 92504192) return;

  hipMemsetAsync(counts, 0, 64, stream);

  convert_x_kernel<<<4096, 256, 0, stream>>>(x, x_bf);
  gating_kernel<<<1024, 256, 0, stream>>>(x, wg, counts, imp, bucket, tok_e, tok_p, tok_g);
  finalize_kernel<<<1, 64, 0, stream>>>(counts, imp, cf, offs, y + (size_t)B_TOK * D_DIM);

  for (int p = 0; p < 2; ++p) {
    // W1 cols [p*2048, +2048) -> wt[e][2048][1024]
    transpose_w_kernel<<<dim3(16, 32, 8), 256, 0, stream>>>(
        W1, wt, H_DIM, 0, p * H_HALF, D_DIM,
        (size_t)D_DIM * H_DIM, (size_t)H_HALF * D_DIM);
    grouped_gemm<D_DIM, H_HALF, true, true, false>
        <<<dim3(H_HALF / 128, 32, N_EXP), 256, 0, stream>>>(
            x_bf, wt, b1 + p * H_HALF, H_DIM, counts, offs, bucket, h_half, H_HALF);
    // W2 rows k in [p*2048, +2048), all n -> wt[e][1024][2048]
    transpose_w_kernel<<<dim3(32, 16, 8), 256, 0, stream>>>(
        W2, wt, D_DIM, p * H_HALF, 0, H_HALF,
        (size_t)H_DIM * D_DIM, (size_t)D_DIM * H_HALF);
    if (p == 0)
      grouped_gemm<H_HALF, D_DIM, false, false, false>
          <<<dim3(D_DIM / 128, 32, N_EXP), 256, 0, stream>>>(
              h_half, wt, b2, D_DIM, counts, offs, bucket, o_buf, D_DIM);
    else
      grouped_gemm<H_HALF, D_DIM, false, false, true>
          <<<dim3(D_DIM / 128, 32, N_EXP), 256, 0, stream>>>(
              h_half, wt, b2, D_DIM, counts, offs, bucket, o_buf, D_DIM);
  }

  combine_kernel<<<4096, 256, 0, stream>>>(o_buf, offs, tok_e, tok_p, tok_g, y);
}

// Round 3
// 662.956 us; speedup vs baseline: 1.2603x; 1.2603x over previous
//
#include <hip/hip_runtime.h>

// MoE top-2 of 8 experts. B=4096 tokens, D=1024, H=4096.
// Round 3: atomic-free gating (ballot counting-sort in one block) +
// coalesced weight transpose. GEMMs unchanged (m97-style global_load_lds).

typedef __attribute__((ext_vector_type(8))) short short8;
typedef __attribute__((ext_vector_type(4))) float f32x4;

#define B_TOK 4096
#define D_DIM 1024
#define H_DIM 4096
#define N_EXP 8
#define H_HALF 2048

__device__ __forceinline__ unsigned short f2bf(float f) {
  unsigned int u = __float_as_uint(f);
  u += 0x7fffu + ((u >> 16) & 1u);  // RNE
  return (unsigned short)(u >> 16);
}
__device__ __forceinline__ float bf2f(unsigned short s) {
  return __uint_as_float(((unsigned int)s) << 16);
}

__device__ __forceinline__ void async_ld16(const void* g, void* l) {
  __builtin_amdgcn_global_load_lds(
      (const __attribute__((address_space(1))) void*)g,
      (__attribute__((address_space(3))) void*)l, 16, 0, 0);
}

// ---------------- x -> bf16 ----------------
__global__ __launch_bounds__(256) void convert_x_kernel(const float* __restrict__ x,
                                                        unsigned short* __restrict__ xb) {
  const size_t i = ((size_t)blockIdx.x * 256 + threadIdx.x) * 4;
  float4 v = *(const float4*)(x + i);
  ushort4 r;
  r.x = f2bf(v.x); r.y = f2bf(v.y); r.z = f2bf(v.z); r.w = f2bf(v.w);
  *(ushort4*)(xb + i) = r;
}

// ---------------- gating compute: fp64 logits, top-2 (NO atomics) ----------------
__global__ __launch_bounds__(256) void gating_kernel(
    const float* __restrict__ x, const float* __restrict__ wg,
    int* __restrict__ tok_e, float* __restrict__ tok_g) {
  const int lane = threadIdx.x & 63;
  const int t = blockIdx.x * 4 + (threadIdx.x >> 6);
  const float* xr = x + (size_t)t * D_DIM;
  double acc[8] = {0, 0, 0, 0, 0, 0, 0, 0};
  for (int d = lane; d < D_DIM; d += 64) {
    double xv = (double)xr[d];
    const float4 w0 = *(const float4*)(wg + d * 8);
    const float4 w1 = *(const float4*)(wg + d * 8 + 4);
    acc[0] += xv * (double)w0.x; acc[1] += xv * (double)w0.y;
    acc[2] += xv * (double)w0.z; acc[3] += xv * (double)w0.w;
    acc[4] += xv * (double)w1.x; acc[5] += xv * (double)w1.y;
    acc[6] += xv * (double)w1.z; acc[7] += xv * (double)w1.w;
  }
#pragma unroll
  for (int e = 0; e < 8; ++e) {
    double v = acc[e];
#pragma unroll
    for (int m = 32; m > 0; m >>= 1) v += __shfl_xor(v, m, 64);
    acc[e] = v;
  }
  if (lane == 0) {
    double b1v = -1e300, b2v = -1e300;
    int i1 = 0, i2 = 0;
#pragma unroll
    for (int e = 0; e < 8; ++e) {
      double v = acc[e];
      if (v > b1v) { b2v = b1v; i2 = i1; b1v = v; i1 = e; }
      else if (v > b2v) { b2v = v; i2 = e; }
    }
    float ex = expf((float)b2v - (float)b1v);
    float den = 1.f + ex;
    tok_e[2 * t] = i1; tok_e[2 * t + 1] = i2;
    tok_g[2 * t] = 1.f / den; tok_g[2 * t + 1] = ex / den;
  }
}

// ---------------- route: single-block counting sort + loss ----------------
__global__ __launch_bounds__(1024) void route_kernel(
    const int* __restrict__ tok_e, const float* __restrict__ tok_g,
    int* __restrict__ tok_p, int* __restrict__ bucket,
    int* __restrict__ counts, int* __restrict__ offs,
    const float* __restrict__ coef, float* __restrict__ loss_out) {
  __shared__ int wavecnt[16][8];
  __shared__ int wavebase[16][8];
  __shared__ int run[8];
  __shared__ float impl[8];
  const int tid = threadIdx.x, lane = tid & 63, wv = tid >> 6;
  if (tid < 8) { run[tid] = 0; impl[tid] = 0.f; }
  __syncthreads();
  for (int c = 0; c < 8; ++c) {
    const int i = c * 1024 + tid;
    const int e = tok_e[i];
    const float g = tok_g[i];
    int rank = 0;
#pragma unroll
    for (int ee = 0; ee < 8; ++ee) {
      unsigned long long m = __ballot(e == ee);
      if (e == ee) rank = __popcll(m & ((1ull << lane) - 1ull));
      float s = (e == ee) ? g : 0.f;
#pragma unroll
      for (int o = 32; o > 0; o >>= 1) s += __shfl_xor(s, o, 64);
      if (lane == 0) {
        wavecnt[wv][ee] = __popcll(m);
        impl[ee] += 0.f;  // touch
        atomicAdd(&impl[ee], s);
      }
    }
    __syncthreads();
    if (tid < 8) {
      int base = run[tid];
      for (int w = 0; w < 16; ++w) { wavebase[w][tid] = base; base += wavecnt[w][tid]; }
      run[tid] = base;
    }
    __syncthreads();
    const int pos = wavebase[wv][e] + rank;
    tok_p[i] = pos;
    bucket[e * B_TOK + pos] = i >> 1;
  }
  __syncthreads();
  if (tid == 0) {
    int o = 0;
    double mi = 0, ml = 0;
    for (int e = 0; e < 8; ++e) {
      counts[e] = run[e]; offs[e] = o; o += run[e];
      mi += (double)impl[e]; ml += (double)run[e];
    }
    offs[8] = o;
    mi *= 0.125; ml *= 0.125;
    double vi = 0, vl = 0;
    for (int e = 0; e < 8; ++e) {
      double di = (double)impl[e] - mi; vi += di * di;
      double dl = (double)run[e]  - ml; vl += dl * dl;
    }
    vi /= 7.0; vl /= 7.0;
    *loss_out = (float)((vi / (mi * mi + 1e-10) + vl / (ml * ml + 1e-10)) * (double)coef[0]);
  }
}

// ---------------- weight transpose: fp32 [k][n] -> bf16 [n][k], coalesced ----------------
__global__ __launch_bounds__(256) void transpose_w_kernel(
    const float* __restrict__ W, unsigned short* __restrict__ Wt,
    int ND_src, int k_base, int n_base, int KD_out,
    size_t w_stride_e, size_t wt_stride_e) {
  const int e = blockIdx.z;
  const int kt = blockIdx.x * 64;
  const int nt = blockIdx.y * 64;
  const float* We = W + (size_t)e * w_stride_e + (size_t)(k_base + kt) * ND_src + n_base + nt;
  unsigned short* Wte = Wt + (size_t)e * wt_stride_e + (size_t)nt * KD_out + kt;
  __shared__ unsigned int Ul[64][36];  // [n][k-pair]; 144B rows (16B aligned)
  const int t = threadIdx.x;
  const int cb = (t & 15) * 4;  // n within tile; lanes 0..15 sweep a 256B row
#pragma unroll
  for (int j = 0; j < 2; ++j) {
    const int p = (t >> 4) + j * 16;  // k-pair 0..31
    float4 f0 = *(const float4*)(We + (size_t)(2 * p) * ND_src + cb);
    float4 f1 = *(const float4*)(We + (size_t)(2 * p + 1) * ND_src + cb);
#pragma unroll
    for (int i2 = 0; i2 < 4; ++i2) {
      unsigned int u = (unsigned int)f2bf(((const float*)&f0)[i2]) |
                       ((unsigned int)f2bf(((const float*)&f1)[i2]) << 16);
      Ul[cb + i2][p] = u;
    }
  }
  __syncthreads();
  const int on = t >> 2;         // out n row
  const int om = (t & 3) * 8;    // 8 uints = 16 k elems = 32B
  uint4 a = *(const uint4*)&Ul[on][om];
  uint4 b = *(const uint4*)&Ul[on][om + 4];
  uint4* dst = (uint4*)(Wte + (size_t)on * KD_out + om * 2);
  dst[0] = a; dst[1] = b;
}

// ---------------- grouped GEMM: 128x128 tile, BK=32, global_load_lds ----------------
template <int KDIM, int NDIM, bool GATHER, bool RELU, bool ACCUM>
__global__ __launch_bounds__(256) void grouped_gemm(
    const unsigned short* __restrict__ A, const unsigned short* __restrict__ Bt,
    const float* __restrict__ bias, int biasN,
    const int* __restrict__ counts, const int* __restrict__ offs,
    const int* __restrict__ bucket, unsigned short* __restrict__ Out, int outN) {
  const int e = blockIdx.z;
  const int n_e = counts[e];
  const int row0 = blockIdx.y * 128;
  if (row0 >= n_e) return;
  const int m_cnt = min(128, n_e - row0);
  const int n0 = blockIdx.x * 128;
  const int slot0 = offs[e] + row0;

  __shared__ unsigned short Alds[128][32];
  __shared__ unsigned short Blds[128][32];
  __shared__ int toklds[128];

  const int tid = threadIdx.x;
  const int lane = tid & 63;
  const int wid = tid >> 6;
  const int q = lane >> 4, l15 = lane & 15;
  const int wm = (wid >> 1) * 64, wn = (wid & 1) * 64;

  if (GATHER) {
    if (tid < 128) toklds[tid] = bucket[e * B_TOK + row0 + min(tid, m_cnt - 1)];
    __syncthreads();
  }
  const int r0 = tid >> 2;
  const int kc = (tid & 3) * 8;
  size_t ga0, ga1;
  if (GATHER) {
    ga0 = (size_t)toklds[r0] * KDIM + kc;
    ga1 = (size_t)toklds[r0 + 64] * KDIM + kc;
  } else {
    ga0 = (size_t)(slot0 + min(r0, m_cnt - 1)) * KDIM + kc;
    ga1 = (size_t)(slot0 + min(r0 + 64, m_cnt - 1)) * KDIM + kc;
  }
  const unsigned short* bbase =
      Bt + (size_t)e * NDIM * KDIM + (size_t)(n0 + r0) * KDIM + kc;
  char* aldsw = (char*)Alds + wid * 1024;
  char* bldsw = (char*)Blds + wid * 1024;

  f32x4 acc[4][4] = {};
  for (int k0 = 0; k0 < KDIM; k0 += 32) {
    async_ld16(A + ga0 + k0, aldsw);
    async_ld16(A + ga1 + k0, aldsw + 4096);
    async_ld16(bbase + k0, bldsw);
    async_ld16(bbase + (size_t)64 * KDIM + k0, bldsw + 4096);
    __syncthreads();
    short8 af[4], bfr[4];
#pragma unroll
    for (int mi = 0; mi < 4; ++mi) af[mi] = *(const short8*)&Alds[wm + mi * 16 + l15][q * 8];
#pragma unroll
    for (int ni = 0; ni < 4; ++ni) bfr[ni] = *(const short8*)&Blds[wn + ni * 16 + l15][q * 8];
#pragma unroll
    for (int mi = 0; mi < 4; ++mi)
#pragma unroll
      for (int ni = 0; ni < 4; ++ni)
        acc[mi][ni] = __builtin_amdgcn_mfma_f32_16x16x32_bf16(af[mi], bfr[ni], acc[mi][ni], 0, 0, 0);
    __syncthreads();
  }

  const float* be = bias + (size_t)e * biasN + n0;
#pragma unroll
  for (int ni = 0; ni < 4; ++ni) {
    const int c = wn + ni * 16 + l15;
    const float bv = ACCUM ? 0.f : be[c];
#pragma unroll
    for (int mi = 0; mi < 4; ++mi) {
      const int rb = wm + mi * 16 + q * 4;
#pragma unroll
      for (int rg = 0; rg < 4; ++rg) {
        const int r = rb + rg;
        if (r < m_cnt) {
          float v = acc[mi][ni][rg] + bv;
          if (RELU) v = fmaxf(v, 0.f);
          unsigned short* op = Out + (size_t)(slot0 + r) * outN + n0 + c;
          if (ACCUM) v += bf2f(*op);
          *op = f2bf(v);
        }
      }
    }
  }
}

// ---------------- combine ----------------
__device__ __forceinline__ float comb1(float a, float b, float g1, float g2) {
  float c = g1 * expf(a) + g2 * expf(b);
  if (c == 0.f) c = 2.220446049250313e-16f;
  return logf(c);
}

__global__ __launch_bounds__(256) void combine_kernel(
    const unsigned short* __restrict__ o_buf, const int* __restrict__ offs,
    const int* __restrict__ tok_e, const int* __restrict__ tok_p,
    const float* __restrict__ tok_g, float* __restrict__ y) {
  const int t = blockIdx.x;
  const int e1 = tok_e[2 * t], e2 = tok_e[2 * t + 1];
  const int s1 = offs[e1] + tok_p[2 * t];
  const int s2 = offs[e2] + tok_p[2 * t + 1];
  const float g1 = tok_g[2 * t], g2 = tok_g[2 * t + 1];
  const int i = threadIdx.x * 4;
  ushort4 a4 = *(const ushort4*)(o_buf + (size_t)s1 * D_DIM + i);
  ushort4 b4 = *(const ushort4*)(o_buf + (size_t)s2 * D_DIM + i);
  float4 r;
  r.x = comb1(bf2f(a4.x), bf2f(b4.x), g1, g2);
  r.y = comb1(bf2f(a4.y), bf2f(b4.y), g1, g2);
  r.z = comb1(bf2f(a4.z), bf2f(b4.z), g1, g2);
  r.w = comb1(bf2f(a4.w), bf2f(b4.w), g1, g2);
  *(float4*)(y + (size_t)t * D_DIM + i) = r;
}

// ---------------- launch ----------------
extern "C" void kernel_launch(void* const* d_in, const int* in_sizes, int n_in,
                              void* d_out, int out_size, void* d_ws, size_t ws_size,
                              hipStream_t stream) {
  const float* x  = (const float*)d_in[0];
  const float* wg = (const float*)d_in[1];
  const float* W1 = (const float*)d_in[2];
  const float* b1 = (const float*)d_in[3];
  const float* W2 = (const float*)d_in[4];
  const float* b2 = (const float*)d_in[5];
  const float* cf = (const float*)d_in[6];
  float* y = (float*)d_out;

  char* w = (char*)d_ws;
  unsigned short* x_bf = (unsigned short*)(w);              // 8,388,608 B
  int*   counts = (int*)(w + 8388608);
  int*   offs   = (int*)(w + 8388672);
  int*   tok_e  = (int*)(w + 8388736);
  int*   tok_p  = (int*)(w + 8421504);
  float* tok_g  = (float*)(w + 8454272);
  int*   bucket = (int*)(w + 8487040);                      // ends 8,618,112
  unsigned short* wt     = (unsigned short*)(w + 8618112);  // 33,554,432 B
  unsigned short* h_half = (unsigned short*)(w + 42172544); // 33,554,432 B
  unsigned short* o_buf  = (unsigned short*)(w + 75726976); // 16,777,216 B
  if (ws_size < 92504192) return;

  convert_x_kernel<<<4096, 256, 0, stream>>>(x, x_bf);
  gating_kernel<<<1024, 256, 0, stream>>>(x, wg, tok_e, tok_g);
  route_kernel<<<1, 1024, 0, stream>>>(tok_e, tok_g, tok_p, bucket, counts, offs,
                                       cf, y + (size_t)B_TOK * D_DIM);

  for (int p = 0; p < 2; ++p) {
    transpose_w_kernel<<<dim3(16, 32, 8), 256, 0, stream>>>(
        W1, wt, H_DIM, 0, p * H_HALF, D_DIM,
        (size_t)D_DIM * H_DIM, (size_t)H_HALF * D_DIM);
    grouped_gemm<D_DIM, H_HALF, true, true, false>
        <<<dim3(H_HALF / 128, 32, N_EXP), 256, 0, stream>>>(
            x_bf, wt, b1 + p * H_HALF, H_DIM, counts, offs, bucket, h_half, H_HALF);
    transpose_w_kernel<<<dim3(32, 16, 8), 256, 0, stream>>>(
        W2, wt, D_DIM, p * H_HALF, 0, H_HALF,
        (size_t)H_DIM * D_DIM, (size_t)D_DIM * H_HALF);
    if (p == 0)
      grouped_gemm<H_HALF, D_DIM, false, false, false>
          <<<dim3(D_DIM / 128, 32, N_EXP), 256, 0, stream>>>(
              h_half, wt, b2, D_DIM, counts, offs, bucket, o_buf, D_DIM);
    else
      grouped_gemm<H_HALF, D_DIM, false, false, true>
          <<<dim3(D_DIM / 128, 32, N_EXP), 256, 0, stream>>>(
              h_half, wt, b2, D_DIM, counts, offs, bucket, o_buf, D_DIM);
  }

  combine_kernel<<<4096, 256, 0, stream>>>(o_buf, offs, tok_e, tok_p, tok_g, y);
}